// Round 5
// baseline (269.685 us; speedup 1.0000x reference)
//
#include <hip/hip_runtime.h>

typedef unsigned short u16;
typedef __attribute__((ext_vector_type(8))) short bf16x8;
typedef __attribute__((ext_vector_type(8))) short s16x8;
typedef __attribute__((ext_vector_type(4))) float f32x4;
typedef __attribute__((ext_vector_type(4))) short s16x4;

#define OUTW 8448  // 256 + 64*128

static __device__ __forceinline__ float bf2f(u16 u) {
    union { unsigned int i; float f; } x; x.i = ((unsigned int)u) << 16; return x.f;
}
static __device__ __forceinline__ u16 f2bf(float f) {
    union { float f; unsigned int i; } x; x.f = f;
    unsigned int lsb = (x.i >> 16) & 1u;
    return (u16)((x.i + 0x7fffu + lsb) >> 16);
}
// LDS column swizzle for Ksm (u16 index, 8-aligned cols): permutes 16B slots
// within each 128B group. Conflict-free for row-wide reads (uniform XOR) and
// beta-step 8x8 blocks (rows (l&7)*8+i -> per-lane distinct slots). (r3-r4)
static __device__ __forceinline__ int kswz(int r, int c) {
    return c ^ (((r ^ (r >> 3)) & 7) << 3);
}

// ============================================================
// Kernel P: (blocks 0..11)  pack [Wf|Ws] -> Bp bf16 [12][192][64]
//           (blocks 12..267) v_global partials = x[:,0,:] @ Wt (f32, k-split 8)
// ============================================================
__global__ __launch_bounds__(256) void k_pre(
    const float* __restrict__ x, const float* __restrict__ Wf, const float* __restrict__ Ws,
    const float* __restrict__ Wt, u16* __restrict__ Bp, float* __restrict__ vg)
{
    const int bid = blockIdx.x, tid = threadIdx.x;
    if (bid < 12) {
        __shared__ float Wl[64][193];   // k-slab transposed staging (+1 pad col)
        const int t = bid;
        #pragma unroll 4
        for (int i = 0; i < 32; ++i) {
            const int idx = i * 256 + tid, r = idx >> 7, c = idx & 127;
            Wl[r][c] = Wf[(size_t)(t * 64 + r) * 128 + c];
        }
        #pragma unroll 4
        for (int i = 0; i < 16; ++i) {
            const int idx = i * 256 + tid, r = idx >> 6, c = idx & 63;
            Wl[r][128 + c] = Ws[(size_t)(t * 64 + r) * 64 + c];
        }
        __syncthreads();
        #pragma unroll
        for (int i = 0; i < 6; ++i) {
            const int ch = i * 256 + tid, c = ch >> 3, j0 = (ch & 7) << 3;
            u16 pk[8];
            #pragma unroll
            for (int j = 0; j < 8; ++j) pk[j] = f2bf(Wl[j0 + j][c]);
            *(s16x8*)&Bp[((size_t)t * 192 + c) * 64 + j0] = *(const s16x8*)pk;
        }
    } else {
        const int blk = bid - 12;
        const int kc = blk >> 5, b = blk & 31, d = tid;
        const float* xr = x + (size_t)b * (1025 * 768) + kc * 96;
        const float* wp = Wt + (size_t)kc * 96 * 256 + d;
        float acc = 0.f;
        #pragma unroll 8
        for (int k = 0; k < 96; ++k) acc += xr[k] * wp[(size_t)k * 256];
        vg[(size_t)blk * 256 + d] = acc;
    }
}

// ============================================================
// Kernel A: X(32768 x 768) @ Bp(768 x 192), bf16 MFMA.
// PANEL-STAGE: block = 32 tokens x 192 cols, 256 thr (4 waves, one
// 48-col slice each). The WHOLE 32x768 A-panel is staged to LDS in one
// burst, then ONE __syncthreads, then a BARRIER-FREE K-loop (12 steps:
// LDS A-frags + L2 B-frags + MFMA). No per-step vmcnt(0) drain -- the
// r1-r4 invariant 65-70us was the per-step barrier sawtooth.
// ============================================================
__global__ __launch_bounds__(256, 3) void k_gemm1(
    const float* __restrict__ x, const u16* __restrict__ Bp,
    const float* __restrict__ bf_, const float* __restrict__ bs_, const float* __restrict__ sharp,
    u16* __restrict__ fT, float* __restrict__ sM)
{
    __shared__ u16 Asm[32][776];   // 49664 B; row stride 1552B -> 2-way bank alias (free)
    const int tid  = threadIdx.x;
    const int lane = tid & 63;
    const int w    = tid >> 6;          // 0..3 = 48-col N-slice
    const int b    = blockIdx.x >> 5;
    const int n0   = (blockIdx.x & 31) << 5;
    const float* Abase = x + ((size_t)b * 1025 + 1 + n0) * 768;  // fi = x[:,1:]

    // ---- stage whole A panel: 6144 float4 slots, 24/thread, coalesced ----
    #pragma unroll
    for (int j = 0; j < 24; ++j) {
        const int slot = j * 256 + tid;         // 0..6143
        const int r = slot / 192, f4 = slot - r * 192;
        const float4 v = *(const float4*)(Abase + (size_t)r * 768 + f4 * 4);
        u16 pk[4];
        pk[0] = f2bf(v.x); pk[1] = f2bf(v.y); pk[2] = f2bf(v.z); pk[3] = f2bf(v.w);
        *(s16x4*)&Asm[r][f4 * 4] = *(const s16x4*)pk;
    }
    __syncthreads();   // the ONLY barrier

    // ---- barrier-free K-loop ----
    f32x4 acc[2][3] = {};
    const int fk = (lane >> 4) << 3;
    const int al = lane & 15;
    const u16* bbase = Bp + (size_t)(w * 48 + al) * 64 + fk;
    #pragma unroll 3
    for (int ks = 0; ks < 12; ++ks) {
        const u16* bp = bbase + (size_t)ks * 12288;
        bf16x8 bfr[6];
        #pragma unroll
        for (int nt = 0; nt < 3; ++nt)
            #pragma unroll
            for (int kk = 0; kk < 2; ++kk)
                bfr[nt * 2 + kk] = *(const bf16x8*)(bp + nt * 1024 + kk * 32);
        #pragma unroll
        for (int kk = 0; kk < 2; ++kk) {
            const int kb = ks * 64 + kk * 32 + fk;
            const bf16x8 af0 = *(const bf16x8*)&Asm[al][kb];
            const bf16x8 af1 = *(const bf16x8*)&Asm[16 + al][kb];
            #pragma unroll
            for (int nt = 0; nt < 3; ++nt) {
                acc[0][nt] = __builtin_amdgcn_mfma_f32_16x16x32_bf16(af0, bfr[nt * 2 + kk], acc[0][nt], 0, 0, 0);
                acc[1][nt] = __builtin_amdgcn_mfma_f32_16x16x32_bf16(af1, bfr[nt * 2 + kk], acc[1][nt], 0, 0, 0);
            }
        }
    }

    // epilogue: token = n0 + mt*16 + (lane>>4)*4 + r ; col = w*48 + nt*16 + (lane&15)
    const int rbase = (lane >> 4) << 2;
    const float sc = sharp[0] * 10.0f;  // sharpness / REG
    #pragma unroll
    for (int mt = 0; mt < 2; ++mt) {
        const int nbase = n0 + mt * 16 + rbase;
        #pragma unroll
        for (int nt = 0; nt < 3; ++nt) {
            const int col16 = w * 48 + nt * 16;   // 16-aligned; never straddles 128
            const int c = col16 + al;
            if (col16 < 128) {
                const float bias = bf_[c];
                u16 pk[4];
                #pragma unroll
                for (int r = 0; r < 4; ++r) pk[r] = f2bf(acc[mt][nt][r] + bias);
                *(s16x4*)&fT[((size_t)b * 128 + c) * 1024 + nbase] = *(const s16x4*)pk;
            } else {
                const int cm = c - 128;
                const float bias = bs_[cm];
                float4 v;
                v.x = (acc[mt][nt][0] + bias) * sc;
                v.y = (acc[mt][nt][1] + bias) * sc;
                v.z = (acc[mt][nt][2] + bias) * sc;
                v.w = (acc[mt][nt][3] + bias) * sc;
                *(float4*)&sM[((size_t)b * 64 + cm) * 1024 + nbase] = v;
            }
        }
    }
}

// ============================================================
// Kernel S: per-batch Sinkhorn (32 blocks x 1024 thr). Validated r1-r4.
//  K = exp(M-rowmax) bf16 LDS (kswz); 5x {alpha; beta}; writes p bf16 + rs.
//  dust row == 1 implicit; dust_bin cancels from p[0:64].
// ============================================================
__global__ __launch_bounds__(1024, 1) void k_sink(
    const float* __restrict__ sM, u16* __restrict__ p_out, float* __restrict__ rs_out)
{
    __shared__ u16   Ksm[64][1024];
    __shared__ float betas[1024];     // permuted: betas[l + m*64 + j*512] = beta[8l+512j+m]
    __shared__ float alph[68];
    const int b = blockIdx.x, tid = threadIdx.x, l = tid & 63, w = tid >> 6;
    const float* Mb = sM + (size_t)b * 64 * 1024;

    #pragma unroll
    for (int i = 0; i < 4; ++i) {
        const int c = w * 4 + i;
        float v[16];
        #pragma unroll
        for (int q = 0; q < 4; ++q)
            *(float4*)(v + q * 4) = *(const float4*)(Mb + (size_t)c * 1024 + l * 16 + q * 4);
        float mx = v[0];
        #pragma unroll
        for (int j = 1; j < 16; ++j) mx = fmaxf(mx, v[j]);
        #pragma unroll
        for (int off = 32; off > 0; off >>= 1) mx = fmaxf(mx, __shfl_xor(mx, off));
        u16 e[16];
        #pragma unroll
        for (int j = 0; j < 16; ++j) e[j] = f2bf(__expf(v[j] - mx));
        *(s16x8*)&Ksm[c][kswz(c, l * 16)]     = *(const s16x8*)(e);
        *(s16x8*)&Ksm[c][kswz(c, l * 16 + 8)] = *(const s16x8*)(e + 8);
    }
    betas[tid] = 1.0f;
    __syncthreads();

    const float a_c = 1.0f / 1024.0f, a_dust = 960.0f / 1024.0f, b_n = 1.0f / 1024.0f;
    const int r8  = (l & 7) * 8;
    const int cg  = w * 8 + (l >> 3);
    const int bwi = (cg & 63) + ((cg >> 6) << 9);

    for (int it = 0; it < 5; ++it) {
        float bb[16];
        #pragma unroll
        for (int j = 0; j < 2; ++j)
            #pragma unroll
            for (int m = 0; m < 8; ++m)
                bb[j * 8 + m] = betas[l + m * 64 + j * 512];
        float sb = 0.f;
        #pragma unroll
        for (int j = 0; j < 16; ++j) sb += bb[j];
        #pragma unroll
        for (int off = 32; off > 0; off >>= 1) sb += __shfl_xor(sb, off);
        #pragma unroll
        for (int i = 0; i < 4; ++i) {
            const int c = w * 4 + i;
            float s = 0.f;
            #pragma unroll
            for (int j = 0; j < 2; ++j) {
                const bf16x8 kr = *(const bf16x8*)&Ksm[c][kswz(c, 8 * l + 512 * j)];
                #pragma unroll
                for (int m = 0; m < 8; ++m) s += bf2f((u16)kr[m]) * bb[j * 8 + m];
            }
            #pragma unroll
            for (int off = 32; off > 0; off >>= 1) s += __shfl_xor(s, off);
            if (l == 0) alph[c] = a_c / s;
        }
        if (tid == 0) alph[64] = a_dust / sb;
        __syncthreads();
        f32x4 a0 = *(const f32x4*)&alph[r8];
        f32x4 a1 = *(const f32x4*)&alph[r8 + 4];
        const float ad = alph[64];
        float sc8[8] = {};
        #pragma unroll
        for (int i = 0; i < 8; ++i) {
            const bf16x8 kb = *(const bf16x8*)&Ksm[r8 + i][kswz(r8 + i, cg * 8)];
            const float av = (i < 4) ? a0[i] : a1[i - 4];
            #pragma unroll
            for (int m = 0; m < 8; ++m) sc8[m] += bf2f((u16)kb[m]) * av;
        }
        #pragma unroll
        for (int off = 1; off < 8; off <<= 1)
            #pragma unroll
            for (int m = 0; m < 8; ++m) sc8[m] += __shfl_xor(sc8[m], off);
        if ((l & 7) == 0) {
            #pragma unroll
            for (int m = 0; m < 8; ++m) betas[bwi + m * 64] = b_n / (sc8[m] + ad);
        }
        __syncthreads();
    }

    // final: p = alpha*K*beta -> global (coalesced), rs = alpha*(K beta)
    float bb[16];
    #pragma unroll
    for (int j = 0; j < 2; ++j)
        #pragma unroll
        for (int m = 0; m < 8; ++m)
            bb[j * 8 + m] = betas[l + m * 64 + j * 512];
    #pragma unroll
    for (int i = 0; i < 4; ++i) {
        const int c = w * 4 + i;
        const float ac = alph[c];
        float s = 0.f;
        u16 pk[16];
        #pragma unroll
        for (int j = 0; j < 2; ++j) {
            const bf16x8 kr = *(const bf16x8*)&Ksm[c][kswz(c, 8 * l + 512 * j)];
            #pragma unroll
            for (int m = 0; m < 8; ++m) {
                const float tv = bf2f((u16)kr[m]) * bb[j * 8 + m];
                s += tv;
                pk[j * 8 + m] = f2bf(ac * tv);
            }
        }
        #pragma unroll
        for (int off = 32; off > 0; off >>= 1) s += __shfl_xor(s, off);
        if (l == 0) rs_out[b * 64 + c] = ac * s;
        u16* pg = p_out + ((size_t)b * 64 + c) * 1024 + 8 * l;   // col 8l+512j+m
        *(s16x8*)(pg)       = *(const s16x8*)(pk);
        *(s16x8*)(pg + 512) = *(const s16x8*)(pk + 8);
    }
}

// ============================================================
// Kernel D: v_agg = 2*p@f - rs*anchors on 256 blocks (b x 8 d-groups).
// Block = 4 waves; wave w -> c-rows w*16..+15, d = dg*16..+15, full K.
// Writes UNNORMALIZED v_local + per-(b,dg) partial sum-of-squares.
// ============================================================
__global__ __launch_bounds__(256) void k_agg(
    const u16* __restrict__ p, const u16* __restrict__ fT,
    const float* __restrict__ rs, const float* __restrict__ anchors,
    float* __restrict__ out, float* __restrict__ ssp)
{
    const int b = blockIdx.x >> 3, dg = blockIdx.x & 7;
    const int tid = threadIdx.x, l = tid & 63, w = tid >> 6;
    const int fk = (l >> 4) << 3;
    const u16* arow = p  + ((size_t)b * 64  + w * 16 + (l & 15)) * 1024 + fk;
    const u16* brow = fT + ((size_t)b * 128 + dg * 16 + (l & 15)) * 1024 + fk;
    f32x4 acc = {};
    #pragma unroll 8
    for (int ks = 0; ks < 32; ++ks) {
        const bf16x8 a  = *(const bf16x8*)(arow + ks * 32);
        const bf16x8 bb = *(const bf16x8*)(brow + ks * 32);
        acc = __builtin_amdgcn_mfma_f32_16x16x32_bf16(a, bb, acc, 0, 0, 0);
    }
    const int d = dg * 16 + (l & 15);
    float ssl = 0.f;
    #pragma unroll
    for (int r = 0; r < 4; ++r) {
        const int c = w * 16 + ((l >> 4) << 2) + r;
        const float vv = 2.0f * acc[r] - rs[b * 64 + c] * anchors[c * 128 + d];
        out[(size_t)b * OUTW + 256 + (size_t)c * 128 + d] = vv;
        ssl += vv * vv;
    }
    #pragma unroll
    for (int off = 32; off > 0; off >>= 1) ssl += __shfl_xor(ssl, off);
    __shared__ float part[4];
    if (l == 0) part[w] = ssl;
    __syncthreads();
    if (tid == 0) ssp[b * 8 + dg] = part[0] + part[1] + part[2] + part[3];
}

// ============================================================
// Kernel E: v_global assemble (+bt), total ss, scale full row
// ============================================================
__global__ __launch_bounds__(256) void k_norm(
    const float* __restrict__ vg, const float* __restrict__ bt,
    const float* __restrict__ ssp, float* __restrict__ out)
{
    const int b = blockIdx.x, t = threadIdx.x;
    float v = bt[t];
    #pragma unroll
    for (int kc = 0; kc < 8; ++kc) v += vg[(size_t)(kc * 32 + b) * 256 + t];
    float ss = v * v;
    #pragma unroll
    for (int off = 32; off > 0; off >>= 1) ss += __shfl_xor(ss, off);
    __shared__ float part[4];
    if ((t & 63) == 0) part[t >> 6] = ss;
    __syncthreads();
    float tot = part[0] + part[1] + part[2] + part[3];
    #pragma unroll
    for (int i = 0; i < 8; ++i) tot += ssp[b * 8 + i];
    const float inv = 1.0f / fmaxf(sqrtf(tot), 1e-12f);
    out[(size_t)b * OUTW + t] = v * inv;
    float* row = out + (size_t)b * OUTW + 256;
    #pragma unroll 8
    for (int j = 0; j < 32; ++j) {
        const int idx = j * 256 + t;
        row[idx] *= inv;
    }
}

extern "C" void kernel_launch(void* const* d_in, const int* in_sizes, int n_in,
                              void* d_out, int out_size, void* d_ws, size_t ws_size,
                              hipStream_t stream)
{
    const float* x      = (const float*)d_in[0];
    const float* Wf     = (const float*)d_in[1];
    const float* bf_    = (const float*)d_in[2];
    const float* Ws     = (const float*)d_in[3];
    const float* bs_    = (const float*)d_in[4];
    const float* Wt     = (const float*)d_in[5];
    const float* bt     = (const float*)d_in[6];
    const float* anchors= (const float*)d_in[7];
    // d_in[8] = dust_bin: cancels out of p[0:64] (constant row potential)
    const float* sharp  = (const float*)d_in[9];

    char* ws = (char*)d_ws;
    u16*   fT = (u16*)(ws);                 //  8,388,608 B : f^T bf16 (B,128,1024)
    float* sM = (float*)(ws + 8388608);     //  8,388,608 B : M f32   (B,64,1024)
    u16*   Bp = (u16*)(ws + 16777216);      //    294,912 B : packed B bf16 [12][192][64]
    float* vg = (float*)(ws + 17072128);    //    262,144 B : v_global partials (8,32,256)
    float* rs = (float*)(ws + 17334272);    //      8,192 B : rowsums (32,64)
    u16*   p  = (u16*)(ws + 17342464);      //  4,194,304 B : p bf16 (B,64,1024)
    float* ssp= (float*)(ws + 21536768);    //      1,024 B : ss partials (32,8)
    float* out = (float*)d_out;

    k_pre  <<<dim3(268),  256,  0, stream>>>(x, Wf, Ws, Wt, Bp, vg);
    k_gemm1<<<dim3(1024), 256,  0, stream>>>(x, Bp, bf_, bs_, sharp, fT, sM);
    k_sink <<<dim3(32),   1024, 0, stream>>>(sM, p, rs);
    k_agg  <<<dim3(256),  256,  0, stream>>>(p, fT, rs, anchors, out, ssp);
    k_norm <<<dim3(32),   256,  0, stream>>>(vg, bt, ssp, out);
}